// Round 1
// baseline (917.315 us; speedup 1.0000x reference)
//
#include <hip/hip_runtime.h>

// Correctly-rounded float decay constants
#define DEC1 0.36787944117144233f   // exp(-1)    : psp1 decay, layer1 refractory
#define DEC2 0.60653065971263342f   // exp(-1/2)  : psp2 decay, layer2 refractory
#define DEC3 0.77880078307140487f   // exp(-1/4)  : psp3 decay, layer3 refractory

// ---------------------------------------------------------------------------
// Weight re-layout into d_ws so the main kernel's weight reads are wave-uniform
// (scalar K$ loads):  w1r[c][ky][kx][o] (400 f)  w2r[c][ky][kx][o] (576 f)
// wupr[o][di][dj][c] pre-flipped for conv_transpose (64 f).  Total 1040 floats.
// ---------------------------------------------------------------------------
__global__ void prep_weights(const float* __restrict__ w1,
                             const float* __restrict__ w2,
                             const float* __restrict__ wup,
                             float* __restrict__ wr)
{
    int i = blockIdx.x * 256 + threadIdx.x;
    if (i < 400) {
        int o = i & 7, tap = i >> 3;
        int c = tap / 25, rem = tap % 25, ky = rem / 5, kx = rem % 5;
        wr[i] = w1[((o * 2 + c) * 5 + ky) * 5 + kx];
    }
    if (i < 576) {
        int o = i & 7, tap = i >> 3;
        int c = tap / 9, rem = tap % 9, ky = rem / 3, kx = rem % 3;
        wr[400 + i] = w2[((o * 8 + c) * 3 + ky) * 3 + kx];
    }
    if (i < 64) {
        // dst index i = ((o*2+di)*2+dj)*8 + c ; conv_transpose (VALID,s=2,k=2,
        // no kernel flip) gives out[2i+di] += x[i]*w[1-di]  -> store flipped.
        int c = i & 7, r = i >> 3;
        int dj = r & 1, di = (r >> 1) & 1, o = r >> 2;
        wr[976 + i] = wup[((o * 8 + c) * 2 + (1 - di)) * 2 + (1 - dj)];
    }
}

// spike + following psp, 4 consecutive timesteps (u = float4 over t)
static __device__ __forceinline__ float4 spike_psp4(float4 u, float th, float dref,
                                                    float dq, float& r, float& q)
{
    float4 qv; float v, s;
    v = __fadd_rn(u.x, r); s = (v >= th) ? 1.f : 0.f;
    r = __fsub_rn(__fmul_rn(dref, r), __fmul_rn(th, s));
    q = __fadd_rn(__fmul_rn(dq, q), s); qv.x = q;
    v = __fadd_rn(u.y, r); s = (v >= th) ? 1.f : 0.f;
    r = __fsub_rn(__fmul_rn(dref, r), __fmul_rn(th, s));
    q = __fadd_rn(__fmul_rn(dq, q), s); qv.y = q;
    v = __fadd_rn(u.z, r); s = (v >= th) ? 1.f : 0.f;
    r = __fsub_rn(__fmul_rn(dref, r), __fmul_rn(th, s));
    q = __fadd_rn(__fmul_rn(dq, q), s); qv.z = q;
    v = __fadd_rn(u.w, r); s = (v >= th) ? 1.f : 0.f;
    r = __fsub_rn(__fmul_rn(dref, r), __fmul_rn(th, s));
    q = __fadd_rn(__fmul_rn(dq, q), s); qv.w = q;
    return qv;
}

// final spike (emits hard spikes), 4 timesteps
static __device__ __forceinline__ float4 spike4(float4 u, float th, float dref, float& r)
{
    float4 ov; float v, s;
    v = __fadd_rn(u.x, r); s = (v >= th) ? 1.f : 0.f;
    r = __fsub_rn(__fmul_rn(dref, r), __fmul_rn(th, s)); ov.x = s;
    v = __fadd_rn(u.y, r); s = (v >= th) ? 1.f : 0.f;
    r = __fsub_rn(__fmul_rn(dref, r), __fmul_rn(th, s)); ov.y = s;
    v = __fadd_rn(u.z, r); s = (v >= th) ? 1.f : 0.f;
    r = __fsub_rn(__fmul_rn(dref, r), __fmul_rn(th, s)); ov.z = s;
    v = __fadd_rn(u.w, r); s = (v >= th) ? 1.f : 0.f;
    r = __fsub_rn(__fmul_rn(dref, r), __fmul_rn(th, s)); ov.w = s;
    return ov;
}

// ---------------------------------------------------------------------------
// Fused SNN megakernel. One block = one (batch, 8x8 spatial tile). Loops T in
// chunks of 4 (float4 along contiguous T). All recurrent state in registers;
// psp tiles staged in LDS with halo recomputation:
//   psp1 region 14x14 (halo 3), psp2 region 10x10 (halo 1), psp3 core 8x8.
// Out-of-image halo pixels are exactly zero end-to-end (zero-pad convs of zero
// psp never reach threshold), so no special-casing beyond zeroed loads.
// ---------------------------------------------------------------------------
__global__ __launch_bounds__(256, 2)
void snn_fused(const float* __restrict__ spk,
               const float* __restrict__ wr,
               float* __restrict__ out)
{
    const int tid  = threadIdx.x;
    const int b    = blockIdx.x >> 6;
    const int tile = blockIdx.x & 63;
    const int gy0  = (tile >> 3) << 3;
    const int gx0  = (tile & 7) << 3;

    __shared__ float4 sP1[196 * 2];  // [14*14 px][2 ch]  (float4 = 4 timesteps)
    __shared__ float4 sP2[100 * 8];  // [10*10 px][8 ch]
    __shared__ float4 sP3[64 * 8];   // [ 8* 8 px][8 ch]

    // persistent per-thread recurrent state
    float aP0 = 0.f, aP1 = 0.f;      // stage A psp1 state (2 input ch)
    float rB[4], qB[4];              // stage B refractory + psp2 (4 out ch)
    float rC[4], qC[4];              // stage C refractory + psp3 (4 out ch)
    float r3[4];                     // stage D refractory (4 subpixels, 1 ch)
#pragma unroll
    for (int i = 0; i < 4; ++i) { rB[i]=0.f; qB[i]=0.f; rC[i]=0.f; qC[i]=0.f; r3[i]=0.f; }

    // ---- stage A addressing: psp1 region 14x14, threads 0..195 ----
    const int ary = tid / 14, arx = tid % 14;
    const int aiy = gy0 - 3 + ary, aix = gx0 - 3 + arx;
    const bool avalid = (tid < 196) && (aiy >= 0) && (aiy < 64) && (aix >= 0) && (aix < 64);
    const int aoff0 = avalid ? (((b * 2 + 0) * 64 + aiy) * 64 + aix) * 200 : 0;
    const int aoff1 = avalid ? (((b * 2 + 1) * 64 + aiy) * 64 + aix) * 200 : 0;

    // ---- stage B: conv1(5x5)+spike1+psp2 on 10x10; waves{0,1}=ch0-3, {2,3}=ch4-7
    const int ochB = __builtin_amdgcn_readfirstlane(tid >> 7);
    const int bpx  = tid & 127;
    const int by   = bpx / 10, bx = bpx % 10;

    // ---- stage C: conv2(3x3)+spike2+psp3 on 8x8; wave0=ch0-3, wave1=ch4-7
    const int ochC = __builtin_amdgcn_readfirstlane(tid >> 6) & 1;
    const int cpx  = tid & 63;
    const int cy   = cpx >> 3, cx = cpx & 7;

    // ---- stage D: convT + bilinear-up + spike3; wave0=out ch0, wave1=out ch1
    const int od   = __builtin_amdgcn_readfirstlane(tid >> 6);
    const int dy   = cpx >> 3, dxx = cpx & 7;
    const int diy  = gy0 + dy, dix = gx0 + dxx;

    // bilinear 2x upsample weights (jax.image.resize "linear": half-pixel
    // centers, edge weights renormalized -> out edge = in edge exactly)
    const float wy0_0 = (diy == 0)  ? 0.f : 0.25f;
    const float wy1_0 = (diy == 0)  ? 1.f : 0.75f;
    const float wy0_1 = (diy == 63) ? 1.f : 0.75f;
    const float wy1_1 = (diy == 63) ? 0.f : 0.25f;
    const float wx0_0 = (dix == 0)  ? 0.f : 0.25f;
    const float wx1_0 = (dix == 0)  ? 1.f : 0.75f;
    const float wx0_1 = (dix == 63) ? 1.f : 0.75f;
    const float wx1_1 = (dix == 63) ? 0.f : 0.25f;

#pragma unroll 1
    for (int ck = 0; ck < 50; ++ck) {
        const int t0 = ck * 4;

        // ================= stage A: psp1 (leaky integrate input spikes) ====
        if (tid < 196) {
            float4 x0, x1;
            if (avalid) {
                x0 = *(const float4*)(spk + aoff0 + t0);
                x1 = *(const float4*)(spk + aoff1 + t0);
            } else {
                x0 = make_float4(0.f, 0.f, 0.f, 0.f);
                x1 = x0;
            }
            float4 v0, v1;
            v0.x = __fadd_rn(__fmul_rn(DEC1, aP0),  x0.x);
            v0.y = __fadd_rn(__fmul_rn(DEC1, v0.x), x0.y);
            v0.z = __fadd_rn(__fmul_rn(DEC1, v0.y), x0.z);
            v0.w = __fadd_rn(__fmul_rn(DEC1, v0.z), x0.w);
            aP0 = v0.w;
            v1.x = __fadd_rn(__fmul_rn(DEC1, aP1),  x1.x);
            v1.y = __fadd_rn(__fmul_rn(DEC1, v1.x), x1.y);
            v1.z = __fadd_rn(__fmul_rn(DEC1, v1.y), x1.z);
            v1.w = __fadd_rn(__fmul_rn(DEC1, v1.z), x1.w);
            aP1 = v1.w;
            sP1[tid * 2 + 0] = v0;
            sP1[tid * 2 + 1] = v1;
        }
        __syncthreads();

        // ================= stage B: conv1 5x5 + spike1 + psp2 ==============
        if (bpx < 100) {
            float4 acc[4];
#pragma unroll
            for (int j = 0; j < 4; ++j) acc[j] = make_float4(0.f, 0.f, 0.f, 0.f);
            const float* wB = wr + ochB * 4;
#pragma unroll 1
            for (int c = 0; c < 2; ++c) {
#pragma unroll 1
                for (int ky = 0; ky < 5; ++ky) {
                    const float4* rowp = &sP1[((by + ky) * 14 + bx) * 2 + c];
                    const float*  wrow = wB + (c * 25 + ky * 5) * 8;
#pragma unroll
                    for (int kx = 0; kx < 5; ++kx) {
                        float4 d = rowp[kx * 2];
#pragma unroll
                        for (int j = 0; j < 4; ++j) {
                            float w = wrow[kx * 8 + j];
                            acc[j].x += w * d.x; acc[j].y += w * d.y;
                            acc[j].z += w * d.z; acc[j].w += w * d.w;
                        }
                    }
                }
            }
#pragma unroll
            for (int j = 0; j < 4; ++j) {
                float4 qv = spike_psp4(acc[j], 30.f, DEC1, DEC2, rB[j], qB[j]);
                sP2[bpx * 8 + ochB * 4 + j] = qv;
            }
        }
        __syncthreads();

        // ================= stage C: conv2 3x3 + spike2 + psp3 ==============
        if (tid < 128) {
            float4 acc[4];
#pragma unroll
            for (int j = 0; j < 4; ++j) acc[j] = make_float4(0.f, 0.f, 0.f, 0.f);
            const float* wC = wr + 400 + ochC * 4;
#pragma unroll 1
            for (int c = 0; c < 8; ++c) {
#pragma unroll 1
                for (int ky = 0; ky < 3; ++ky) {
                    const float4* rowp = &sP2[((cy + ky) * 10 + cx) * 8 + c];
                    const float*  wrow = wC + (c * 9 + ky * 3) * 8;
#pragma unroll
                    for (int kx = 0; kx < 3; ++kx) {
                        float4 d = rowp[kx * 8];
#pragma unroll
                        for (int j = 0; j < 4; ++j) {
                            float w = wrow[kx * 8 + j];
                            acc[j].x += w * d.x; acc[j].y += w * d.y;
                            acc[j].z += w * d.z; acc[j].w += w * d.w;
                        }
                    }
                }
            }
#pragma unroll
            for (int j = 0; j < 4; ++j) {
                float4 qv = spike_psp4(acc[j], 50.f, DEC2, DEC3, rC[j], qC[j]);
                sP3[cpx * 8 + ochC * 4 + j] = qv;
            }
        }
        __syncthreads();

        // ============ stage D: convT 2x2 s2 + psp1 bilinear-up + spike3 ====
        if (tid < 128) {
            float4 p3[8];
#pragma unroll
            for (int c = 0; c < 8; ++c) p3[c] = sP3[cpx * 8 + c];
            float4 P[3][3];   // psp1 3x3 neighborhood, channel = od
#pragma unroll
            for (int sy = 0; sy < 3; ++sy)
#pragma unroll
            for (int sx = 0; sx < 3; ++sx)
                P[sy][sx] = sP1[((dy + 2 + sy) * 14 + (dxx + 2 + sx)) * 2 + od];

#pragma unroll
            for (int di = 0; di < 2; ++di) {
                const float ay  = di ? wy0_1 : wy0_0;
                const float byw = di ? wy1_1 : wy1_0;
#pragma unroll
                for (int dj = 0; dj < 2; ++dj) {
                    const float ax  = dj ? wx0_1 : wx0_0;
                    const float bxw = dj ? wx1_1 : wx1_0;
                    // conv_transpose contribution (pre-flipped weights)
                    float4 tv = make_float4(0.f, 0.f, 0.f, 0.f);
                    const float* wD = wr + 976 + ((od * 2 + di) * 2 + dj) * 8;
#pragma unroll
                    for (int c = 0; c < 8; ++c) {
                        float w = wD[c];
                        tv.x += w * p3[c].x; tv.y += w * p3[c].y;
                        tv.z += w * p3[c].z; tv.w += w * p3[c].w;
                    }
                    // bilinear upsample: y-interp first (resize does H then W)
                    float4 A = P[di][dj],     Bv = P[di][dj + 1];
                    float4 Cv = P[di + 1][dj], Dv = P[di + 1][dj + 1];
                    float4 up, u;
                    float ra, rb;
                    ra = __fadd_rn(__fmul_rn(ay, A.x),  __fmul_rn(byw, Cv.x));
                    rb = __fadd_rn(__fmul_rn(ay, Bv.x), __fmul_rn(byw, Dv.x));
                    up.x = __fadd_rn(__fmul_rn(ax, ra), __fmul_rn(bxw, rb));
                    ra = __fadd_rn(__fmul_rn(ay, A.y),  __fmul_rn(byw, Cv.y));
                    rb = __fadd_rn(__fmul_rn(ay, Bv.y), __fmul_rn(byw, Dv.y));
                    up.y = __fadd_rn(__fmul_rn(ax, ra), __fmul_rn(bxw, rb));
                    ra = __fadd_rn(__fmul_rn(ay, A.z),  __fmul_rn(byw, Cv.z));
                    rb = __fadd_rn(__fmul_rn(ay, Bv.z), __fmul_rn(byw, Dv.z));
                    up.z = __fadd_rn(__fmul_rn(ax, ra), __fmul_rn(bxw, rb));
                    ra = __fadd_rn(__fmul_rn(ay, A.w),  __fmul_rn(byw, Cv.w));
                    rb = __fadd_rn(__fmul_rn(ay, Bv.w), __fmul_rn(byw, Dv.w));
                    up.w = __fadd_rn(__fmul_rn(ax, ra), __fmul_rn(bxw, rb));

                    u.x = __fadd_rn(tv.x, up.x);
                    u.y = __fadd_rn(tv.y, up.y);
                    u.z = __fadd_rn(tv.z, up.z);
                    u.w = __fadd_rn(tv.w, up.w);

                    const int sub = di * 2 + dj;
                    float4 ov = spike4(u, 100.f, DEC3, r3[sub]);
                    float* op = out + ((((b * 2 + od) * 128 + (2 * diy + di)) * 128)
                                       + (2 * dix + dj)) * 200 + t0;
                    *(float4*)op = ov;
                }
            }
        }
        __syncthreads();  // protect sP1/sP3 before next chunk overwrites
    }
}

extern "C" void kernel_launch(void* const* d_in, const int* in_sizes, int n_in,
                              void* d_out, int out_size, void* d_ws, size_t ws_size,
                              hipStream_t stream)
{
    const float* spk = (const float*)d_in[0];
    const float* w1  = (const float*)d_in[1];
    const float* w2  = (const float*)d_in[2];
    const float* wup = (const float*)d_in[3];
    float* outp = (float*)d_out;
    float* wr   = (float*)d_ws;   // 1040 floats of re-laid-out weights

    prep_weights<<<dim3(3), dim3(256), 0, stream>>>(w1, w2, wup, wr);
    snn_fused<<<dim3(512), dim3(256), 0, stream>>>(spk, wr, outp);
}

// Round 2
// 726.034 us; speedup vs baseline: 1.2635x; 1.2635x over previous
//
#include <hip/hip_runtime.h>

// Correctly-rounded float decay constants
#define DEC1 0.36787944117144233f   // exp(-1)    : psp1 decay, layer1 refractory
#define DEC2 0.60653065971263342f   // exp(-1/2)  : psp2 decay, layer2 refractory
#define DEC3 0.77880078307140487f   // exp(-1/4)  : psp3 decay, layer3 refractory

// ---------------------------------------------------------------------------
// Weight re-layout into d_ws so the main kernel's weight reads are wave-uniform
// (scalar K$ loads):  w1r[c][ky][kx][o] (400 f)  w2r[c][ky][kx][o] (576 f)
// wupr[o][di][dj][c] pre-flipped for conv_transpose (64 f).  Total 1040 floats.
// ---------------------------------------------------------------------------
__global__ void prep_weights(const float* __restrict__ w1,
                             const float* __restrict__ w2,
                             const float* __restrict__ wup,
                             float* __restrict__ wr)
{
    int i = blockIdx.x * 256 + threadIdx.x;
    if (i < 400) {
        int o = i & 7, tap = i >> 3;
        int c = tap / 25, rem = tap % 25, ky = rem / 5, kx = rem % 5;
        wr[i] = w1[((o * 2 + c) * 5 + ky) * 5 + kx];
    }
    if (i < 576) {
        int o = i & 7, tap = i >> 3;
        int c = tap / 9, rem = tap % 9, ky = rem / 3, kx = rem % 3;
        wr[400 + i] = w2[((o * 8 + c) * 3 + ky) * 3 + kx];
    }
    if (i < 64) {
        // dst index i = ((o*2+di)*2+dj)*8 + c ; conv_transpose (VALID,s=2,k=2,
        // no kernel flip) gives out[2i+di] += x[i]*w[1-di]  -> store flipped.
        int c = i & 7, r = i >> 3;
        int dj = r & 1, di = (r >> 1) & 1, o = r >> 2;
        wr[976 + i] = wup[((o * 8 + c) * 2 + (1 - di)) * 2 + (1 - dj)];
    }
}

// spike + following psp, 4 consecutive timesteps (u = float4 over t)
static __device__ __forceinline__ float4 spike_psp4(float4 u, float th, float dref,
                                                    float dq, float& r, float& q)
{
    float4 qv; float v, s;
    v = __fadd_rn(u.x, r); s = (v >= th) ? 1.f : 0.f;
    r = __fsub_rn(__fmul_rn(dref, r), __fmul_rn(th, s));
    q = __fadd_rn(__fmul_rn(dq, q), s); qv.x = q;
    v = __fadd_rn(u.y, r); s = (v >= th) ? 1.f : 0.f;
    r = __fsub_rn(__fmul_rn(dref, r), __fmul_rn(th, s));
    q = __fadd_rn(__fmul_rn(dq, q), s); qv.y = q;
    v = __fadd_rn(u.z, r); s = (v >= th) ? 1.f : 0.f;
    r = __fsub_rn(__fmul_rn(dref, r), __fmul_rn(th, s));
    q = __fadd_rn(__fmul_rn(dq, q), s); qv.z = q;
    v = __fadd_rn(u.w, r); s = (v >= th) ? 1.f : 0.f;
    r = __fsub_rn(__fmul_rn(dref, r), __fmul_rn(th, s));
    q = __fadd_rn(__fmul_rn(dq, q), s); qv.w = q;
    return qv;
}

// final spike (emits hard spikes), 4 timesteps
static __device__ __forceinline__ float4 spike4(float4 u, float th, float dref, float& r)
{
    float4 ov; float v, s;
    v = __fadd_rn(u.x, r); s = (v >= th) ? 1.f : 0.f;
    r = __fsub_rn(__fmul_rn(dref, r), __fmul_rn(th, s)); ov.x = s;
    v = __fadd_rn(u.y, r); s = (v >= th) ? 1.f : 0.f;
    r = __fsub_rn(__fmul_rn(dref, r), __fmul_rn(th, s)); ov.y = s;
    v = __fadd_rn(u.z, r); s = (v >= th) ? 1.f : 0.f;
    r = __fsub_rn(__fmul_rn(dref, r), __fmul_rn(th, s)); ov.z = s;
    v = __fadd_rn(u.w, r); s = (v >= th) ? 1.f : 0.f;
    r = __fsub_rn(__fmul_rn(dref, r), __fmul_rn(th, s)); ov.w = s;
    return ov;
}

// ---------------------------------------------------------------------------
// Fused SNN megakernel. One block = one (batch, 8x8 spatial tile). Loops T in
// chunks of 4 (float4 along contiguous T). All recurrent state in registers;
// psp tiles staged in LDS with halo recomputation:
//   psp1 region 14x14 (halo 3), psp2 region 10x10 (halo 1), psp3 core 8x8.
// LDS layout is [ch][px] (SoA): consecutive lanes access consecutive float4s
// (16 B lane stride) -> bank-conflict-free ds_read_b128 / ds_write_b128.
// [px][ch] (R0) had a 128 B lane stride = all lanes on the same 4 banks,
// SQ_LDS_BANK_CONFLICT 2.65e8 (~55% of kernel cycles on the LDS pipe).
// ---------------------------------------------------------------------------
__global__ __launch_bounds__(256, 2)
void snn_fused(const float* __restrict__ spk,
               const float* __restrict__ wr,
               float* __restrict__ out)
{
    const int tid  = threadIdx.x;
    const int b    = blockIdx.x >> 6;
    const int tile = blockIdx.x & 63;
    const int gy0  = (tile >> 3) << 3;
    const int gx0  = (tile & 7) << 3;

    __shared__ float4 sP1[2 * 196];  // [2 ch][14*14 px]  (float4 = 4 timesteps)
    __shared__ float4 sP2[8 * 100];  // [8 ch][10*10 px]
    __shared__ float4 sP3[8 * 64];   // [8 ch][ 8* 8 px]

    // persistent per-thread recurrent state
    float aP0 = 0.f, aP1 = 0.f;      // stage A psp1 state (2 input ch)
    float rB[4], qB[4];              // stage B refractory + psp2 (4 out ch)
    float rC[4], qC[4];              // stage C refractory + psp3 (4 out ch)
    float r3[4];                     // stage D refractory (4 subpixels, 1 ch)
#pragma unroll
    for (int i = 0; i < 4; ++i) { rB[i]=0.f; qB[i]=0.f; rC[i]=0.f; qC[i]=0.f; r3[i]=0.f; }

    // ---- stage A addressing: psp1 region 14x14, threads 0..195 ----
    const int ary = tid / 14, arx = tid % 14;
    const int aiy = gy0 - 3 + ary, aix = gx0 - 3 + arx;
    const bool avalid = (tid < 196) && (aiy >= 0) && (aiy < 64) && (aix >= 0) && (aix < 64);
    const int aoff0 = avalid ? (((b * 2 + 0) * 64 + aiy) * 64 + aix) * 200 : 0;
    const int aoff1 = avalid ? (((b * 2 + 1) * 64 + aiy) * 64 + aix) * 200 : 0;

    // ---- stage B: conv1(5x5)+spike1+psp2 on 10x10; waves{0,1}=ch0-3, {2,3}=ch4-7
    const int ochB = __builtin_amdgcn_readfirstlane(tid >> 7);
    const int bpx  = tid & 127;
    const int by   = bpx / 10, bx = bpx % 10;

    // ---- stage C: conv2(3x3)+spike2+psp3 on 8x8; wave0=ch0-3, wave1=ch4-7
    const int ochC = __builtin_amdgcn_readfirstlane(tid >> 6) & 1;
    const int cpx  = tid & 63;
    const int cy   = cpx >> 3, cx = cpx & 7;

    // ---- stage D: convT + bilinear-up + spike3; wave0=out ch0, wave1=out ch1
    const int od   = __builtin_amdgcn_readfirstlane(tid >> 6);
    const int dy   = cpx >> 3, dxx = cpx & 7;
    const int diy  = gy0 + dy, dix = gx0 + dxx;

    // bilinear 2x upsample weights (jax.image.resize "linear": half-pixel
    // centers, edge weights renormalized -> out edge = in edge exactly)
    const float wy0_0 = (diy == 0)  ? 0.f : 0.25f;
    const float wy1_0 = (diy == 0)  ? 1.f : 0.75f;
    const float wy0_1 = (diy == 63) ? 1.f : 0.75f;
    const float wy1_1 = (diy == 63) ? 0.f : 0.25f;
    const float wx0_0 = (dix == 0)  ? 0.f : 0.25f;
    const float wx1_0 = (dix == 0)  ? 1.f : 0.75f;
    const float wx0_1 = (dix == 63) ? 1.f : 0.75f;
    const float wx1_1 = (dix == 63) ? 0.f : 0.25f;

#pragma unroll 1
    for (int ck = 0; ck < 50; ++ck) {
        const int t0 = ck * 4;

        // ================= stage A: psp1 (leaky integrate input spikes) ====
        if (tid < 196) {
            float4 x0, x1;
            if (avalid) {
                x0 = *(const float4*)(spk + aoff0 + t0);
                x1 = *(const float4*)(spk + aoff1 + t0);
            } else {
                x0 = make_float4(0.f, 0.f, 0.f, 0.f);
                x1 = x0;
            }
            float4 v0, v1;
            v0.x = __fadd_rn(__fmul_rn(DEC1, aP0),  x0.x);
            v0.y = __fadd_rn(__fmul_rn(DEC1, v0.x), x0.y);
            v0.z = __fadd_rn(__fmul_rn(DEC1, v0.y), x0.z);
            v0.w = __fadd_rn(__fmul_rn(DEC1, v0.z), x0.w);
            aP0 = v0.w;
            v1.x = __fadd_rn(__fmul_rn(DEC1, aP1),  x1.x);
            v1.y = __fadd_rn(__fmul_rn(DEC1, v1.x), x1.y);
            v1.z = __fadd_rn(__fmul_rn(DEC1, v1.y), x1.z);
            v1.w = __fadd_rn(__fmul_rn(DEC1, v1.z), x1.w);
            aP1 = v1.w;
            sP1[0 * 196 + tid] = v0;
            sP1[1 * 196 + tid] = v1;
        }
        __syncthreads();

        // ================= stage B: conv1 5x5 + spike1 + psp2 ==============
        if (bpx < 100) {
            float4 acc[4];
#pragma unroll
            for (int j = 0; j < 4; ++j) acc[j] = make_float4(0.f, 0.f, 0.f, 0.f);
            const float* wB = wr + ochB * 4;
#pragma unroll 1
            for (int c = 0; c < 2; ++c) {
#pragma unroll 1
                for (int ky = 0; ky < 5; ++ky) {
                    const float4* rowp = &sP1[c * 196 + (by + ky) * 14 + bx];
                    const float*  wrow = wB + (c * 25 + ky * 5) * 8;
#pragma unroll
                    for (int kx = 0; kx < 5; ++kx) {
                        float4 d = rowp[kx];
#pragma unroll
                        for (int j = 0; j < 4; ++j) {
                            float w = wrow[kx * 8 + j];
                            acc[j].x += w * d.x; acc[j].y += w * d.y;
                            acc[j].z += w * d.z; acc[j].w += w * d.w;
                        }
                    }
                }
            }
#pragma unroll
            for (int j = 0; j < 4; ++j) {
                float4 qv = spike_psp4(acc[j], 30.f, DEC1, DEC2, rB[j], qB[j]);
                sP2[(ochB * 4 + j) * 100 + bpx] = qv;
            }
        }
        __syncthreads();

        // ================= stage C: conv2 3x3 + spike2 + psp3 ==============
        if (tid < 128) {
            float4 acc[4];
#pragma unroll
            for (int j = 0; j < 4; ++j) acc[j] = make_float4(0.f, 0.f, 0.f, 0.f);
            const float* wC = wr + 400 + ochC * 4;
#pragma unroll 1
            for (int c = 0; c < 8; ++c) {
#pragma unroll 1
                for (int ky = 0; ky < 3; ++ky) {
                    const float4* rowp = &sP2[c * 100 + (cy + ky) * 10 + cx];
                    const float*  wrow = wC + (c * 9 + ky * 3) * 8;
#pragma unroll
                    for (int kx = 0; kx < 3; ++kx) {
                        float4 d = rowp[kx];
#pragma unroll
                        for (int j = 0; j < 4; ++j) {
                            float w = wrow[kx * 8 + j];
                            acc[j].x += w * d.x; acc[j].y += w * d.y;
                            acc[j].z += w * d.z; acc[j].w += w * d.w;
                        }
                    }
                }
            }
#pragma unroll
            for (int j = 0; j < 4; ++j) {
                float4 qv = spike_psp4(acc[j], 50.f, DEC2, DEC3, rC[j], qC[j]);
                sP3[(ochC * 4 + j) * 64 + cpx] = qv;
            }
        }
        __syncthreads();

        // ============ stage D: convT 2x2 s2 + psp1 bilinear-up + spike3 ====
        if (tid < 128) {
            float4 p3[8];
#pragma unroll
            for (int c = 0; c < 8; ++c) p3[c] = sP3[c * 64 + cpx];
            float4 P[3][3];   // psp1 3x3 neighborhood, channel = od
#pragma unroll
            for (int sy = 0; sy < 3; ++sy)
#pragma unroll
            for (int sx = 0; sx < 3; ++sx)
                P[sy][sx] = sP1[od * 196 + (dy + 2 + sy) * 14 + (dxx + 2 + sx)];

#pragma unroll
            for (int di = 0; di < 2; ++di) {
                const float ay  = di ? wy0_1 : wy0_0;
                const float byw = di ? wy1_1 : wy1_0;
#pragma unroll
                for (int dj = 0; dj < 2; ++dj) {
                    const float ax  = dj ? wx0_1 : wx0_0;
                    const float bxw = dj ? wx1_1 : wx1_0;
                    // conv_transpose contribution (pre-flipped weights)
                    float4 tv = make_float4(0.f, 0.f, 0.f, 0.f);
                    const float* wD = wr + 976 + ((od * 2 + di) * 2 + dj) * 8;
#pragma unroll
                    for (int c = 0; c < 8; ++c) {
                        float w = wD[c];
                        tv.x += w * p3[c].x; tv.y += w * p3[c].y;
                        tv.z += w * p3[c].z; tv.w += w * p3[c].w;
                    }
                    // bilinear upsample: y-interp first (resize does H then W)
                    float4 A = P[di][dj],     Bv = P[di][dj + 1];
                    float4 Cv = P[di + 1][dj], Dv = P[di + 1][dj + 1];
                    float4 up, u;
                    float ra, rb;
                    ra = __fadd_rn(__fmul_rn(ay, A.x),  __fmul_rn(byw, Cv.x));
                    rb = __fadd_rn(__fmul_rn(ay, Bv.x), __fmul_rn(byw, Dv.x));
                    up.x = __fadd_rn(__fmul_rn(ax, ra), __fmul_rn(bxw, rb));
                    ra = __fadd_rn(__fmul_rn(ay, A.y),  __fmul_rn(byw, Cv.y));
                    rb = __fadd_rn(__fmul_rn(ay, Bv.y), __fmul_rn(byw, Dv.y));
                    up.y = __fadd_rn(__fmul_rn(ax, ra), __fmul_rn(bxw, rb));
                    ra = __fadd_rn(__fmul_rn(ay, A.z),  __fmul_rn(byw, Cv.z));
                    rb = __fadd_rn(__fmul_rn(ay, Bv.z), __fmul_rn(byw, Dv.z));
                    up.z = __fadd_rn(__fmul_rn(ax, ra), __fmul_rn(bxw, rb));
                    ra = __fadd_rn(__fmul_rn(ay, A.w),  __fmul_rn(byw, Cv.w));
                    rb = __fadd_rn(__fmul_rn(ay, Bv.w), __fmul_rn(byw, Dv.w));
                    up.w = __fadd_rn(__fmul_rn(ax, ra), __fmul_rn(bxw, rb));

                    u.x = __fadd_rn(tv.x, up.x);
                    u.y = __fadd_rn(tv.y, up.y);
                    u.z = __fadd_rn(tv.z, up.z);
                    u.w = __fadd_rn(tv.w, up.w);

                    const int sub = di * 2 + dj;
                    float4 ov = spike4(u, 100.f, DEC3, r3[sub]);
                    float* op = out + ((((b * 2 + od) * 128 + (2 * diy + di)) * 128)
                                       + (2 * dix + dj)) * 200 + t0;
                    *(float4*)op = ov;
                }
            }
        }
        __syncthreads();  // protect sP1/sP3 before next chunk overwrites
    }
}

extern "C" void kernel_launch(void* const* d_in, const int* in_sizes, int n_in,
                              void* d_out, int out_size, void* d_ws, size_t ws_size,
                              hipStream_t stream)
{
    const float* spk = (const float*)d_in[0];
    const float* w1  = (const float*)d_in[1];
    const float* w2  = (const float*)d_in[2];
    const float* wup = (const float*)d_in[3];
    float* outp = (float*)d_out;
    float* wr   = (float*)d_ws;   // 1040 floats of re-laid-out weights

    prep_weights<<<dim3(3), dim3(256), 0, stream>>>(w1, w2, wup, wr);
    snn_fused<<<dim3(512), dim3(256), 0, stream>>>(spk, wr, outp);
}